// Round 5
// baseline (389.716 us; speedup 1.0000x reference)
//
#include <hip/hip_runtime.h>
#include <hip/hip_bf16.h>

// ---------------------------------------------------------------------------
// RecursiveSortNet — bf16 MFMA pipeline, fully-packed 2-matrix u16 sort:
//   sort: round x to bf16 (monotone => commutes with sort), map to
//         order-preserving u16 keys; pack (even-matrix, odd-matrix) elements
//         into the two halves of one VGPR => EVERY bitonic CE is one
//         v_pk_min_u16 + v_pk_max_u16 (inline asm, R3-hardware-proven).
//   NOTE: no inline-constant VOP3P asm! op_sel_hi=1 default makes a 32-bit
//   inline constant feed bits[31:16] to the high-half op (R4 bug: shift-by-0).
//   h1 = relu(xs @ W1^T + b1)   bf16 MFMA, fp32 acc
//   h2 = relu(h1 @ W2^T + b2)
//   out =      h2 @ W3^T + b3   fp32 out
// ---------------------------------------------------------------------------

#define B_DIM 8192
#define D_DIM 4096
#define H1_DIM 512
#define H2_DIM 256

typedef unsigned int u32;
typedef unsigned short u16;
typedef __attribute__((ext_vector_type(2))) short i16x2;
typedef __attribute__((ext_vector_type(8))) short bf16x8;
typedef __attribute__((ext_vector_type(4))) float f32x4;

__device__ __forceinline__ u16 f2bf(float f) {
    union { float f; unsigned u; } v{f};
    unsigned r = v.u + 0x7FFF + ((v.u >> 16) & 1);   // RNE, finite inputs
    return (u16)(r >> 16);
}

// ---- packed 16-bit min/max, pinned to VOP3P (register-register only) ------
__device__ __forceinline__ u32 pkmin(u32 a, u32 b) {
    u32 d; asm("v_pk_min_u16 %0, %1, %2" : "=v"(d) : "v"(a), "v"(b)); return d;
}
__device__ __forceinline__ u32 pkmax(u32 a, u32 b) {
    u32 d; asm("v_pk_max_u16 %0, %1, %2" : "=v"(d) : "v"(a), "v"(b)); return d;
}
// per-half arithmetic >>15 — compiler-lowered (R3-proven), NOT inline asm.
__device__ __forceinline__ u32 pkashr15(u32 a) {
    union { u32 u; i16x2 v; } x; x.u = a;
    x.v = x.v >> 15;
    return x.u;
}

// two floats (one from even matrix, one from odd) -> packed order-pres. keys
__device__ __forceinline__ u32 key2(float fa, float fb) {
    union { __hip_bfloat162 h; u32 u; } cv;
    cv.h = __float22bfloat162_rn(float2{fa, fb});    // RNE (header-verified)
    u32 bb = cv.u;
    return bb ^ (pkashr15(bb) | 0x80008000u);        // per-half: b ^ ((b>>15)|0x8000)
}

// Bitonic sort of 64 elements; v[i] holds (matA elem i, matB elem i) packed.
// All conditions compile-time; both halves always sort the same direction.
__device__ __forceinline__ void sortnet64(u32 v[64]) {
#pragma unroll
    for (int k = 2; k <= 64; k <<= 1) {
#pragma unroll
        for (int j = k >> 1; j > 0; j >>= 1) {
#pragma unroll
            for (int i = 0; i < 64; ++i) {
                if (i & j) continue;
                const int q = i | j;
                const bool up = ((i & k) == 0);
                u32 mn = pkmin(v[i], v[q]);
                u32 mx = pkmax(v[i], v[q]);
                v[i] = up ? mn : mx;
                v[q] = up ? mx : mn;
            }
        }
    }
}

// One wave per block, TWO matrices per wave (even=low half, odd=high half).
// LDS: 64 rows x 16 segments x 16B = 16 KB; segment s of row r stored at
// position (s ^ (r&15)) => every b32/b128 phase is at the bank-BW floor.
__global__ __launch_bounds__(64)
void sort_kernel(const float* __restrict__ x, u16* __restrict__ xs)
{
    __shared__ u32 S[64 * 64];            // u16x2 units, 16 KB
    const int lane = threadIdx.x;
    const int b    = blockIdx.x;
    const float4* A4 = (const float4*)(x + (size_t)(2 * b)     * D_DIM);
    const float4* B4 = (const float4*)(x + (size_t)(2 * b + 1) * D_DIM);
    u16* dstA = xs + (size_t)(2 * b)     * D_DIM;
    u16* dstB = xs + (size_t)(2 * b + 1) * D_DIM;

    // ---- stage-in: coalesced float4 loads, pack cross-matrix keys, b128 LDS
#pragma unroll
    for (int q = 0; q < 16; ++q) {
        int f = q * 64 + lane;
        float4 a = A4[f], c = B4[f];
        int r = f >> 4, s = f & 15;
        uint4 w;
        w.x = key2(a.x, c.x); w.y = key2(a.y, c.y);
        w.z = key2(a.z, c.z); w.w = key2(a.w, c.w);
        *(uint4*)(S + r * 64 + ((s ^ (r & 15)) << 2)) = w;
    }
    __syncthreads();

    u32 v[64];
    // ---- sort 1: columns (lane = column) ----
#pragma unroll
    for (int p = 0; p < 64; ++p)
        v[p] = S[p * 64 + (((lane >> 2) ^ (p & 15)) << 2) + (lane & 3)];
    sortnet64(v);
    __syncthreads();
#pragma unroll
    for (int p = 0; p < 64; ++p)
        S[p * 64 + (((lane >> 2) ^ (p & 15)) << 2) + (lane & 3)] = v[p];
    __syncthreads();

    // ---- sort 2: rows (lane = row), b128 reads/writes ----
#pragma unroll
    for (int q = 0; q < 16; ++q) {
        uint4 w = *(const uint4*)(S + lane * 64 + ((q ^ (lane & 15)) << 2));
        v[4 * q + 0] = w.x; v[4 * q + 1] = w.y;
        v[4 * q + 2] = w.z; v[4 * q + 3] = w.w;
    }
    sortnet64(v);
    __syncthreads();
#pragma unroll
    for (int q = 0; q < 16; ++q) {
        uint4 w;
        w.x = v[4 * q + 0]; w.y = v[4 * q + 1];
        w.z = v[4 * q + 2]; w.w = v[4 * q + 3];
        *(uint4*)(S + lane * 64 + ((q ^ (lane & 15)) << 2)) = w;
    }
    __syncthreads();

    // ---- sort 3: columns again ----
#pragma unroll
    for (int p = 0; p < 64; ++p)
        v[p] = S[p * 64 + (((lane >> 2) ^ (p & 15)) << 2) + (lane & 3)];
    sortnet64(v);

    // unmap keys -> bf16 bits: bf = key ^ (~(key>>15 arith) | 0x8000) per half
#pragma unroll
    for (int p = 0; p < 64; ++p)
        v[p] = v[p] ^ (~pkashr15(v[p]) | 0x80008000u);

    __syncthreads();
#pragma unroll
    for (int p = 0; p < 64; ++p)
        S[p * 64 + (((lane >> 2) ^ (p & 15)) << 2) + (lane & 3)] = v[p];
    __syncthreads();

    // ---- stage-out: b128 LDS reads, split halves, coalesced 8B stores ----
#pragma unroll
    for (int q = 0; q < 16; ++q) {
        int f = q * 64 + lane;
        int r = f >> 4, s = f & 15;
        uint4 w = *(const uint4*)(S + r * 64 + ((s ^ (r & 15)) << 2));
        uint2 oa, ob;
        oa.x = (w.x & 0xFFFFu) | (w.y << 16);
        oa.y = (w.z & 0xFFFFu) | (w.w << 16);
        ob.x = (w.x >> 16) | (w.y & 0xFFFF0000u);
        ob.y = (w.z >> 16) | (w.w & 0xFFFF0000u);
        *(uint2*)(dstA + r * 64 + s * 4) = oa;
        *(uint2*)(dstB + r * 64 + s * 4) = ob;
    }
}

// ---------------- fp32 -> bf16 weight conversion ---------------------------
__global__ __launch_bounds__(256)
void cvt_bf16(const float* __restrict__ src, u16* __restrict__ dst, int n4)
{
    int i = blockIdx.x * blockDim.x + threadIdx.x;
    if (i < n4) {
        float4 v = ((const float4*)src)[i];
        ushort4 o;
        o.x = f2bf(v.x); o.y = f2bf(v.y); o.z = f2bf(v.z); o.w = f2bf(v.w);
        ((ushort4*)dst)[i] = o;
    }
}

// ---------------- bf16 MFMA GEMM body: C = act(A @ W^T + bias) -------------
template<int BM, int BN, bool RELU, bool OUT_BF16>
__device__ __forceinline__
void gemm_body(const u16* __restrict__ A, const u16* __restrict__ Wt,
               const float* __restrict__ bias, void* __restrict__ Cout,
               int M, int N, int K)
{
    constexpr int BK  = 64;
    constexpr int WTM = BM / 2, WTN = BN / 2;
    constexpr int FM  = WTM / 16, FN = WTN / 16;
    __shared__ u16 sA[BM * BK];
    __shared__ u16 sB[BN * BK];

    const int tid  = threadIdx.x;
    const int wave = tid >> 6;
    const int lane = tid & 63;
    const int wm   = wave >> 1, wn = wave & 1;
    const int gm0  = blockIdx.y * BM;
    const int gn0  = blockIdx.x * BN;

    const int r_in = lane >> 3;
    const int j_in = lane & 7;

    f32x4 acc[FM][FN] = {};

    for (int k0 = 0; k0 < K; k0 += BK) {
#pragma unroll
        for (int c = 0; c < BM / 32; ++c) {
            int rb  = wave * (BM / 4) + c * 8;
            int r   = rb + r_in;
            int seg = j_in ^ (r & 7);
            const u16* g = A + (size_t)(gm0 + r) * K + k0 + seg * 8;
            __builtin_amdgcn_global_load_lds(
                (const __attribute__((address_space(1))) void*)g,
                (__attribute__((address_space(3))) void*)&sA[rb * 64],
                16, 0, 0);
        }
#pragma unroll
        for (int c = 0; c < BN / 32; ++c) {
            int rb  = wave * (BN / 4) + c * 8;
            int r   = rb + r_in;
            int seg = j_in ^ (r & 7);
            const u16* g = Wt + (size_t)(gn0 + r) * K + k0 + seg * 8;
            __builtin_amdgcn_global_load_lds(
                (const __attribute__((address_space(1))) void*)g,
                (__attribute__((address_space(3))) void*)&sB[rb * 64],
                16, 0, 0);
        }
        __syncthreads();

#pragma unroll
        for (int ks = 0; ks < 2; ++ks) {
            bf16x8 afr[FM], bfr[FN];
#pragma unroll
            for (int i = 0; i < FM; ++i) {
                int m   = wm * WTM + i * 16 + (lane & 15);
                int seg = (ks * 4 + (lane >> 4)) ^ (m & 7);
                afr[i] = *(const bf16x8*)&sA[m * 64 + seg * 8];
            }
#pragma unroll
            for (int j = 0; j < FN; ++j) {
                int n   = wn * WTN + j * 16 + (lane & 15);
                int seg = (ks * 4 + (lane >> 4)) ^ (n & 7);
                bfr[j] = *(const bf16x8*)&sB[n * 64 + seg * 8];
            }
#pragma unroll
            for (int i = 0; i < FM; ++i)
#pragma unroll
                for (int j = 0; j < FN; ++j)
                    acc[i][j] = __builtin_amdgcn_mfma_f32_16x16x32_bf16(
                        afr[i], bfr[j], acc[i][j], 0, 0, 0);
        }
        __syncthreads();
    }

#pragma unroll
    for (int j = 0; j < FN; ++j) {
        int n = gn0 + wn * WTN + j * 16 + (lane & 15);
        float bv = bias[n];
#pragma unroll
        for (int i = 0; i < FM; ++i) {
#pragma unroll
            for (int r = 0; r < 4; ++r) {
                int m = gm0 + wm * WTM + i * 16 + (lane >> 4) * 4 + r;
                float vv = acc[i][j][r] + bv;
                if (RELU) vv = fmaxf(vv, 0.f);
                if (OUT_BF16)
                    ((u16*)Cout)[(size_t)m * N + n] = f2bf(vv);
                else
                    ((float*)Cout)[(size_t)m * N + n] = vv;
            }
        }
    }
}

// Distinctly-named trampolines => per-GEMM attribution in rocprof top-k.
__global__ __launch_bounds__(256, 2)
void gemm1_xs_w1(const u16* A, const u16* Wt, const float* bias, void* C,
                 int M, int N, int K) { gemm_body<128, 64, true, true >(A, Wt, bias, C, M, N, K); }
__global__ __launch_bounds__(256, 2)
void gemm2_h1_w2(const u16* A, const u16* Wt, const float* bias, void* C,
                 int M, int N, int K) { gemm_body<128, 64, true, true >(A, Wt, bias, C, M, N, K); }
__global__ __launch_bounds__(256, 2)
void gemm3_h2_w3(const u16* A, const u16* Wt, const float* bias, void* C,
                 int M, int N, int K) { gemm_body<128, 128, false, false>(A, Wt, bias, C, M, N, K); }

// ---------------------------------------------------------------------------
extern "C" void kernel_launch(void* const* d_in, const int* in_sizes, int n_in,
                              void* d_out, int out_size, void* d_ws, size_t ws_size,
                              hipStream_t stream)
{
    const float* x  = (const float*)d_in[0];
    const float* W1 = (const float*)d_in[1];
    const float* b1 = (const float*)d_in[2];
    const float* W2 = (const float*)d_in[3];
    const float* b2 = (const float*)d_in[4];
    const float* W3 = (const float*)d_in[5];
    const float* b3 = (const float*)d_in[6];

    // xs (bf16, 64 MB) lives in d_out; GEMM3 overwrites d_out after GEMM1 read xs.
    u16* xs = (u16*)d_out;
    char* ws = (char*)d_ws;
    u16* h1b = (u16*)(ws);                      //  8 MB
    u16* h2b = (u16*)(ws + (8u  << 20));        //  4 MB
    u16* W1b = (u16*)(ws + (12u << 20));        //  4 MB
    u16* W2b = (u16*)(ws + (16u << 20));        //  0.25 MB
    u16* W3b = (u16*)(ws + (17u << 20));        //  2 MB

    sort_kernel<<<B_DIM / 2, 64, 0, stream>>>(x, xs);

    cvt_bf16<<<(H1_DIM * D_DIM / 4 + 255) / 256, 256, 0, stream>>>(W1, W1b, H1_DIM * D_DIM / 4);
    cvt_bf16<<<(H2_DIM * H1_DIM / 4 + 255) / 256, 256, 0, stream>>>(W2, W2b, H2_DIM * H1_DIM / 4);
    cvt_bf16<<<(D_DIM * H2_DIM / 4 + 255) / 256, 256, 0, stream>>>(W3, W3b, D_DIM * H2_DIM / 4);

    // h1 = relu(xs @ W1^T + b1)  [8192 x 512, K=4096]  tile 128x64
    gemm1_xs_w1<<<dim3(H1_DIM / 64, B_DIM / 128), 256, 0, stream>>>(
        xs, W1b, b1, h1b, B_DIM, H1_DIM, D_DIM);

    // h2 = relu(h1 @ W2^T + b2)  [8192 x 256, K=512]   tile 128x64
    gemm2_h1_w2<<<dim3(H2_DIM / 64, B_DIM / 128), 256, 0, stream>>>(
        h1b, W2b, b2, h2b, B_DIM, H2_DIM, H1_DIM);

    // out = h2 @ W3^T + b3       [8192 x 4096, K=256]  tile 128x128
    gemm3_h2_w3<<<dim3(D_DIM / 128, B_DIM / 128), 256, 0, stream>>>(
        h2b, W3b, b3, (float*)d_out, B_DIM, D_DIM, H2_DIM);
}